// Round 4
// baseline (448.970 us; speedup 1.0000x reference)
//
#include <hip/hip_runtime.h>
#include <stdint.h>

#define NB 256
#define NQ 900
#define NC 256
#define TOPK 100
#define QC (NQ * NC)      // 230400
#define NBINS 4096
#define CAP 2048
#define FCAP 512
#define KS 20             // sample-suffix target; 1/32 sample -> E[M] ~ 650
#define SHIFT 18          // coarse: float bits >> 18
#define NSROWS 28         // sampled rows (1/32 of 900, q = 32j+16)

// fused = exp(-obj) * sigmoid(logit); classes >= 240 invalid (forced ~0 in ref).
// Two-level sampled threshold (coarse 4096 bins -> fine 4096 bins inside the
// fat bin) -> collect ALL elements >= thr (precise math, identical expression
// to rounds 1-3 which passed exactly) -> exact kth via radix-select -> exact
// rank over ~110 survivors. Any thr with M in [100,CAP] gives exact top-100;
// M-range check + binary-search fallback covers pathological data.

__device__ __forceinline__ float fastsig(float x) {
    return __builtin_amdgcn_rcpf(1.0f + __expf(-x));
}

// one atomic per wave; returns slot or -1
__device__ __forceinline__ int waveAppend(bool pred, int* ctr, int lane) {
    unsigned long long m = __ballot(pred);
    if (m == 0ull) return -1;
    int cnt = __popcll(m);
    int leader = __ffsll(m) - 1;
    int tmp = 0;
    if (lane == leader) tmp = atomicAdd(ctr, cnt);
    int base = __shfl(tmp, leader);
    int off = __popcll(m & ((1ull << lane) - 1ull));
    return pred ? (base + off) : -1;
}

// max bin b with baseCum + suffix(b) >= KSv over hist[0..4095]; *s_next gets
// the cum strictly above that bin. Fully parallel (wave shfl suffix scans).
__device__ __forceinline__ int find_thr_bin(unsigned* hist, unsigned* p2,
                                            unsigned* p2sufA, int* s_res,
                                            int* s_next, int KSv, int baseCum)
{
    const int tid = threadIdx.x;
    const int lane = tid & 63;
    const int w = tid >> 6;
    unsigned h0 = hist[tid * 4 + 0], h1 = hist[tid * 4 + 1];
    unsigned h2 = hist[tid * 4 + 2], h3 = hist[tid * 4 + 3];
    unsigned v = h0 + h1 + h2 + h3;
    unsigned s = v;                       // inclusive suffix over lanes >= lane
    #pragma unroll
    for (int d = 1; d < 64; d <<= 1) {
        unsigned o = __shfl_down(s, d);
        if (lane + d < 64) s += o;
    }
    if (lane == 0) p2[w] = s;             // wave total
    __syncthreads();
    if (tid < 16) {
        unsigned acc = 0;
        for (int k = tid + 1; k < 16; ++k) acc += p2[k];
        p2sufA[tid] = acc;
    }
    __syncthreads();
    unsigned above = (s - v) + p2sufA[w]; // suffix of bins > 4*tid+3
    int nb = baseCum + (int)above;
    int c3 = nb + (int)h3;
    int c2 = c3 + (int)h2;
    int c1 = c2 + (int)h1;
    int c0 = c1 + (int)h0;
    // unique boundary: cum(b) >= KS > cum(b+1) (only a nonempty bin qualifies)
    if (c3 >= KSv && nb < KSv) { *s_res = 4 * tid + 3; *s_next = nb; }
    if (c2 >= KSv && c3 < KSv) { *s_res = 4 * tid + 2; *s_next = c3; }
    if (c1 >= KSv && c2 < KSv) { *s_res = 4 * tid + 1; *s_next = c2; }
    if (c0 >= KSv && c1 < KSv) { *s_res = 4 * tid + 0; *s_next = c1; }
    __syncthreads();
    return *s_res;
}

__global__ __launch_bounds__(1024)
void postproc_kernel(const float* __restrict__ logits,
                     const float* __restrict__ obj,
                     const float* __restrict__ pboxes,
                     const float* __restrict__ tsz,
                     float* __restrict__ out)
{
    const int b = blockIdx.x;
    const int tid = threadIdx.x;
    const int wid = tid >> 6;
    const int lane = tid & 63;

    __shared__ unsigned pool[NBINS];        // 16 KB: coarse/fine hist, later fb/fi
    __shared__ float eobj[NQ];              // 3.6 KB
    __shared__ unsigned cbits[CAP];         // 8 KB
    __shared__ int cidx[CAP];               // 8 KB
    __shared__ unsigned short activeQ[NQ];  // 1.8 KB
    __shared__ unsigned part[1024];         // radix rhist/rsuf
    __shared__ unsigned p2[16], p2sufA[16];
    __shared__ int s_res, s_next, s_cnt, s_nActive, s_c2, s_dig, s_above, s_nfin;

    // ---- init ----
    for (int i = tid; i < NBINS; i += 1024) pool[i] = 0;
    if (tid == 0) { s_cnt = 0; s_nActive = 0; s_nfin = 0; }
    if (tid < NQ) eobj[tid] = expf(-obj[b * NQ + tid]);
    __syncthreads();

    const float4* lg4 = (const float4*)(logits + (size_t)b * QC);

    // ---- A1: coarse sampled histogram (28 rows, wave per row, FAST math) ----
    for (int r = wid; r < NSROWS; r += 16) {
        int q = r * 32 + 16;
        if (lane < 60) {
            float eo = eobj[q];
            float4 v = lg4[(q << 6) + lane];
            atomicAdd(&pool[__float_as_uint(eo * fastsig(v.x)) >> SHIFT], 1u);
            atomicAdd(&pool[__float_as_uint(eo * fastsig(v.y)) >> SHIFT], 1u);
            atomicAdd(&pool[__float_as_uint(eo * fastsig(v.z)) >> SHIFT], 1u);
            atomicAdd(&pool[__float_as_uint(eo * fastsig(v.w)) >> SHIFT], 1u);
        }
    }
    __syncthreads();

    const int T = find_thr_bin(pool, p2, p2sufA, &s_res, &s_next, KS, 0);
    const int aboveT = s_next;            // sample count strictly above bin T

    // ---- A2: fine histogram inside fat bin T (sample rows are L1/L2-hot) ----
    for (int i = tid; i < NBINS; i += 1024) pool[i] = 0;
    __syncthreads();
    const unsigned Tlo = (unsigned)T << SHIFT;
    const unsigned Thi = (unsigned)(T + 1) << SHIFT;
    for (int r = wid; r < NSROWS; r += 16) {
        int q = r * 32 + 16;
        if (lane < 60) {
            float eo = eobj[q];
            float4 v = lg4[(q << 6) + lane];
            unsigned b0 = __float_as_uint(eo * fastsig(v.x));
            unsigned b1 = __float_as_uint(eo * fastsig(v.y));
            unsigned b2 = __float_as_uint(eo * fastsig(v.z));
            unsigned b3 = __float_as_uint(eo * fastsig(v.w));
            if (b0 >= Tlo && b0 < Thi) atomicAdd(&pool[(b0 - Tlo) >> 6], 1u);
            if (b1 >= Tlo && b1 < Thi) atomicAdd(&pool[(b1 - Tlo) >> 6], 1u);
            if (b2 >= Tlo && b2 < Thi) atomicAdd(&pool[(b2 - Tlo) >> 6], 1u);
            if (b3 >= Tlo && b3 < Thi) atomicAdd(&pool[(b3 - Tlo) >> 6], 1u);
        }
    }
    __syncthreads();
    const int FB = find_thr_bin(pool, p2, p2sufA, &s_res, &s_next, KS, aboveT);
    unsigned thrBits = Tlo + ((unsigned)FB << 6);

    // ---- active rows (exact bound: score <= eobj), ballot-compacted ----
    {
        bool pred = (tid < NQ) && (__float_as_uint(eobj[tid]) >= thrBits);
        int pos = waveAppend(pred, &s_nActive, lane);
        if (pos >= 0) activeQ[pos] = (unsigned short)tid;
    }
    __syncthreads();
    const int nA = s_nActive;

    // ---- pass B: collect candidates (PRECISE math — defines outputs) ----
    // wave per row, 2-stage pipelined loads, ballot-aggregated appends
    {
        int j = wid;
        int qcur = -1;
        float4 vcur = make_float4(0.f, 0.f, 0.f, 0.f);
        if (j < nA) {
            int q = activeQ[j];
            if (lane < 60) { qcur = q; vcur = lg4[(q << 6) + lane]; }
        }
        while (j < nA) {
            int jn = j + 16;
            int qn = -1;
            float4 vn = make_float4(0.f, 0.f, 0.f, 0.f);
            if (jn < nA) {
                int q2 = activeQ[jn];
                if (lane < 60) { qn = q2; vn = lg4[(q2 << 6) + lane]; }
            }
            bool val = (qcur >= 0);
            float eo = val ? eobj[qcur] : 0.0f;
            float xs0 = vcur.x, xs1 = vcur.y, xs2 = vcur.z, xs3 = vcur.w;
            #pragma unroll
            for (int j2 = 0; j2 < 4; ++j2) {
                float x = (j2 == 0) ? xs0 : (j2 == 1) ? xs1 : (j2 == 2) ? xs2 : xs3;
                float sres = eo * (1.0f / (1.0f + expf(-x)));
                unsigned bb = __float_as_uint(sres);
                bool pred = val && (bb >= thrBits);
                int pos = waveAppend(pred, &s_cnt, lane);
                if (pos >= 0 && pos < CAP) {
                    cbits[pos] = bb;
                    cidx[pos] = (qcur << 8) + (lane << 2) + j2;
                }
            }
            j = jn; qcur = qn; vcur = vn;
        }
    }
    __syncthreads();
    int M = s_cnt;

    // ---- fallback (exact, any data): binary-search threshold ----
    if (M < TOPK || M > CAP) {
        int lo = 0, hi = NBINS - 1;
        while (lo < hi) {
            int mid = (lo + hi + 1) >> 1;
            unsigned int tb = (unsigned int)mid << SHIFT;
            if (tid == 0) s_c2 = 0;
            __syncthreads();
            int local = 0;
            for (int j = wid; j < NQ; j += 16) {
                if (__float_as_uint(eobj[j]) >= tb && lane < 60) {
                    float eo = eobj[j];
                    float4 v = lg4[(j << 6) + lane];
                    local += (__float_as_uint(eo * (1.0f / (1.0f + expf(-v.x)))) >= tb);
                    local += (__float_as_uint(eo * (1.0f / (1.0f + expf(-v.y)))) >= tb);
                    local += (__float_as_uint(eo * (1.0f / (1.0f + expf(-v.z)))) >= tb);
                    local += (__float_as_uint(eo * (1.0f / (1.0f + expf(-v.w)))) >= tb);
                }
            }
            atomicAdd(&s_c2, local);
            __syncthreads();
            if (s_c2 >= TOPK) lo = mid; else hi = mid - 1;
            __syncthreads();
        }
        unsigned int tb = (unsigned int)lo << SHIFT;
        thrBits = tb;
        if (tid == 0) s_cnt = 0;
        __syncthreads();
        for (int j = wid; j < NQ; j += 16) {
            if (__float_as_uint(eobj[j]) >= tb && lane < 60) {
                float eo = eobj[j];
                float4 v = lg4[(j << 6) + lane];
                #pragma unroll
                for (int j2 = 0; j2 < 4; ++j2) {
                    float x = (j2 == 0) ? v.x : (j2 == 1) ? v.y : (j2 == 2) ? v.z : v.w;
                    float s = eo * (1.0f / (1.0f + expf(-x)));
                    unsigned int bits = __float_as_uint(s);
                    if (bits >= tb) {
                        int p = atomicAdd(&s_cnt, 1);
                        if (p < CAP) {
                            cbits[p] = bits;
                            cidx[p] = (j << 8) + (lane << 2) + j2;
                        }
                    }
                }
            }
        }
        __syncthreads();
        M = s_cnt;
    }
    M = min(M, CAP);

    // ---- radix-select: exact TOPK-th largest bits among cbits[0..M) ----
    unsigned int* rhist = part;          // 256
    unsigned int* rsuf  = part + 256;    // 256
    unsigned int prefixVal = 0;
    int need = TOPK;
    int startShift = 24;
    if ((thrBits >> 24) == 0x3Fu) { prefixVal = 0x3F000000u; startShift = 16; }
    for (int shift = startShift; shift >= 0; shift -= 8) {
        if (tid < 256) rhist[tid] = 0;
        __syncthreads();
        unsigned int pmask = (shift >= 24) ? 0u : (0xFFFFFFFFu << (shift + 8));
        for (int i = tid; i < M; i += 1024) {
            unsigned int bb = cbits[i];
            if ((bb & pmask) == (prefixVal & pmask))
                atomicAdd(&rhist[(bb >> shift) & 255], 1u);
        }
        __syncthreads();
        if (tid < 64) {
            unsigned int h0 = rhist[tid * 4 + 0];
            unsigned int h1 = rhist[tid * 4 + 1];
            unsigned int h2 = rhist[tid * 4 + 2];
            unsigned int h3 = rhist[tid * 4 + 3];
            unsigned int loc = h0 + h1 + h2 + h3;
            unsigned int suf = loc;
            #pragma unroll
            for (int d = 1; d < 64; d <<= 1) {
                unsigned int o = __shfl_down(suf, d);
                suf += (tid + d < 64) ? o : 0u;
            }
            unsigned int above = suf - loc;
            rsuf[tid * 4 + 3] = above + h3;
            rsuf[tid * 4 + 2] = above + h3 + h2;
            rsuf[tid * 4 + 1] = above + h3 + h2 + h1;
            rsuf[tid * 4 + 0] = above + h3 + h2 + h1 + h0;
        }
        __syncthreads();
        if (tid < 256) {
            int sv = (int)rsuf[tid];
            int sa = (tid == 255) ? 0 : (int)rsuf[tid + 1];
            if (sv >= need && sa < need) { s_dig = tid; s_above = sa; }
        }
        __syncthreads();
        prefixVal |= ((unsigned int)s_dig) << shift;
        need -= s_above;
    }
    const unsigned int kth = prefixVal;

    // ---- compact survivors (bits >= kth) ----
    unsigned int* fb = pool;
    int* fi = (int*)(pool + FCAP);
    for (int i = tid; i < M; i += 1024) {
        unsigned int bb = cbits[i];
        if (bb >= kth) {
            int p = atomicAdd(&s_nfin, 1);
            if (p < FCAP) { fb[p] = bb; fi[p] = cidx[i]; }
        }
    }
    __syncthreads();
    const int n = min(s_nfin, FCAP);

    // ---- exact rank over survivors (desc bits, tie -> lower index) ----
    const float ih = tsz[b * 2 + 0];
    const float iw = tsz[b * 2 + 1];
    float* out_scores = out;
    float* out_labels = out + NB * TOPK;
    float* out_boxes  = out + 2 * NB * TOPK;

    for (int i = tid; i < n; i += 1024) {
        unsigned int mb = fb[i];
        int mi = fi[i];
        int rank = 0;
        for (int j = 0; j < n; ++j) {
            unsigned int ob = fb[j];
            int oi = fi[j];
            rank += (ob > mb) || (ob == mb && oi < mi);
        }
        if (rank < TOPK) {
            int q = mi >> 8;
            int c = mi & 255;
            out_scores[b * TOPK + rank] = __uint_as_float(mb);
            out_labels[b * TOPK + rank] = (float)c;
            const float* bp = pboxes + ((size_t)b * NQ + q) * 4;
            float cx = bp[0], cy = bp[1], w = bp[2], h = bp[3];
            float* dst = out_boxes + ((size_t)b * TOPK + rank) * 4;
            dst[0] = (cx - 0.5f * w) * iw;
            dst[1] = (cy - 0.5f * h) * ih;
            dst[2] = (cx + 0.5f * w) * iw;
            dst[3] = (cy + 0.5f * h) * ih;
        }
    }
}

extern "C" void kernel_launch(void* const* d_in, const int* in_sizes, int n_in,
                              void* d_out, int out_size, void* d_ws, size_t ws_size,
                              hipStream_t stream) {
    const float* logits = (const float*)d_in[0];
    const float* obj    = (const float*)d_in[1];
    const float* boxes  = (const float*)d_in[2];
    const float* tsz    = (const float*)d_in[3];
    float* out = (float*)d_out;
    hipLaunchKernelGGL(postproc_kernel, dim3(NB), dim3(1024), 0, stream,
                       logits, obj, boxes, tsz, out);
}

// Round 5
// 40.542 us; speedup vs baseline: 11.0741x; 11.0741x over previous
//
#include <hip/hip_runtime.h>
#include <stdint.h>

#define NB 256
#define NQ 900
#define NC 256
#define TOPK 100
#define QC (NQ * NC)      // 230400
#define NBINS_S 4096
#define CAP 4096
#define FCAP 512
#define KS 25             // sample-suffix target (1/16 sample -> E[M] ~ 400)
#define SHIFT 18          // coarse: float bits >> 18

// fused = exp(-obj) * sigmoid(logit); classes >= 240 invalid (forced ~0 in ref).
// R3 structure (proven) + ONE change: two-level sampled threshold.
// A1: coarse 4096-bin histogram of 1/16-sampled scores (fast math) -> fat bin T.
// A2: fine 4096-bin histogram inside T (sample rows L2-hot) -> thr at 64-ulp
// resolution -> M ~ 400 instead of ~2000, higher thr -> fewer pass-B rows.
// Pass B (precise math, byte-identical to R1-R3) collects all >= thr; exact
// kth via radix-select; exact rank over ~100 survivors; binary-search fallback
// guarantees correctness for any data.

__device__ __forceinline__ float fastsig(float x) {
    return __builtin_amdgcn_rcpf(1.0f + __expf(-x));
}

__global__ __launch_bounds__(1024)
void postproc_kernel(const float* __restrict__ logits,
                     const float* __restrict__ obj,
                     const float* __restrict__ pboxes,
                     const float* __restrict__ tsz,
                     float* __restrict__ out)
{
    const int b = blockIdx.x;
    const int tid = threadIdx.x;
    const int wid = tid >> 6;
    const int lane = tid & 63;

    __shared__ unsigned int pool[NBINS_S];    // 16 KB: coarse/fine hist, later fb/fi
    __shared__ float eobj[NQ];                // 3.6 KB
    __shared__ unsigned int cbits[CAP];       // 16 KB
    __shared__ int cidx[CAP];                 // 16 KB
    __shared__ int activeQ[NQ];               // 3.6 KB
    __shared__ unsigned int part[1024];       // 4 KB: scan scratch, later rhist/rsuf
    __shared__ unsigned int part2[32];
    __shared__ int s_thrBin, s_cnt, s_nActive, s_c2;
    __shared__ int s_dig, s_above, s_nfin;

    unsigned int* shist = pool;

    // ---- init ----
    for (int i = tid; i < NBINS_S; i += 1024) shist[i] = 0;
    if (tid == 0) { s_cnt = 0; s_nActive = 0; }
    if (tid < NQ) eobj[tid] = expf(-obj[b * NQ + tid]);
    __syncthreads();

    const float4* lg4 = (const float4*)(logits + (size_t)b * QC);

    // ---- A1: coarse sampled histogram (56 rows, 1/16), wave per row ----
    for (int j = wid; j < 56; j += 16) {
        int q = j * 16 + 8;
        if (lane < 60) {
            float eo = eobj[q];
            float4 v = lg4[(q << 6) + lane];
            atomicAdd(&shist[__float_as_uint(eo * fastsig(v.x)) >> SHIFT], 1u);
            atomicAdd(&shist[__float_as_uint(eo * fastsig(v.y)) >> SHIFT], 1u);
            atomicAdd(&shist[__float_as_uint(eo * fastsig(v.z)) >> SHIFT], 1u);
            atomicAdd(&shist[__float_as_uint(eo * fastsig(v.w)) >> SHIFT], 1u);
        }
    }
    __syncthreads();

    // ---- walk 1: coarse threshold bin (R3's proven reduce + serial walk) ----
    {
        unsigned int sum = 0;
        #pragma unroll
        for (int j = 0; j < 4; ++j) sum += shist[tid * 4 + j];
        part[tid] = sum;
    }
    __syncthreads();
    if (tid < 32) {
        unsigned int s2 = 0;
        #pragma unroll
        for (int j = 0; j < 32; ++j) s2 += part[tid * 32 + j];
        part2[tid] = s2;
    }
    __syncthreads();
    int cumT = 0;                       // valid in tid 0 only
    if (tid == 0) {
        int cum = 0;
        int sc = 31;
        while (sc > 0 && cum + (int)part2[sc] < KS) { cum += (int)part2[sc]; --sc; }
        int pc = sc * 32 + 31, plo = sc * 32;
        while (pc > plo && cum + (int)part[pc] < KS) { cum += (int)part[pc]; --pc; }
        int bin = pc * 4 + 3, blo = pc * 4;
        while (bin > blo && cum + (int)shist[bin] < KS) { cum += (int)shist[bin]; --bin; }
        s_thrBin = bin;
        cumT = cum;                     // count strictly above bin T
    }
    __syncthreads();
    const int T = s_thrBin;
    const unsigned int Tlo = (unsigned int)T << SHIFT;
    const unsigned int Thi = (unsigned int)(T + 1) << SHIFT;

    // ---- A2: fine histogram inside fat bin T (sample rows are L2-hot) ----
    for (int i = tid; i < NBINS_S; i += 1024) shist[i] = 0;
    __syncthreads();
    for (int j = wid; j < 56; j += 16) {
        int q = j * 16 + 8;
        if (lane < 60) {
            float eo = eobj[q];
            float4 v = lg4[(q << 6) + lane];
            unsigned int b0 = __float_as_uint(eo * fastsig(v.x));
            unsigned int b1 = __float_as_uint(eo * fastsig(v.y));
            unsigned int b2 = __float_as_uint(eo * fastsig(v.z));
            unsigned int b3 = __float_as_uint(eo * fastsig(v.w));
            if (b0 >= Tlo && b0 < Thi) atomicAdd(&shist[(b0 - Tlo) >> 6], 1u);
            if (b1 >= Tlo && b1 < Thi) atomicAdd(&shist[(b1 - Tlo) >> 6], 1u);
            if (b2 >= Tlo && b2 < Thi) atomicAdd(&shist[(b2 - Tlo) >> 6], 1u);
            if (b3 >= Tlo && b3 < Thi) atomicAdd(&shist[(b3 - Tlo) >> 6], 1u);
        }
    }
    __syncthreads();

    // ---- walk 2: fine threshold bin (same reduce+walk, cum starts at cumT) ----
    {
        unsigned int sum = 0;
        #pragma unroll
        for (int j = 0; j < 4; ++j) sum += shist[tid * 4 + j];
        part[tid] = sum;
    }
    __syncthreads();
    if (tid < 32) {
        unsigned int s2 = 0;
        #pragma unroll
        for (int j = 0; j < 32; ++j) s2 += part[tid * 32 + j];
        part2[tid] = s2;
    }
    __syncthreads();
    if (tid == 0) {
        int cum = cumT;
        int sc = 31;
        while (sc > 0 && cum + (int)part2[sc] < KS) { cum += (int)part2[sc]; --sc; }
        int pc = sc * 32 + 31, plo = sc * 32;
        while (pc > plo && cum + (int)part[pc] < KS) { cum += (int)part[pc]; --pc; }
        int bin = pc * 4 + 3, blo = pc * 4;
        while (bin > blo && cum + (int)shist[bin] < KS) { cum += (int)shist[bin]; --bin; }
        s_thrBin = bin;
    }
    __syncthreads();
    unsigned int thrBits = Tlo + ((unsigned int)s_thrBin << 6);

    // ---- active rows (exact bound: score <= eobj) ----
    if (tid < NQ) {
        if (__float_as_uint(eobj[tid]) >= thrBits) {
            int p = atomicAdd(&s_nActive, 1);
            activeQ[p] = tid;
        }
    }
    __syncthreads();
    const int nA = s_nActive;

    // ---- pass B: collect candidates (PRECISE math — defines outputs) ----
    for (int j = wid; j < nA; j += 16) {
        int q = activeQ[j];
        if (lane < 60) {
            float eo = eobj[q];
            float4 v = lg4[(q << 6) + lane];
            #pragma unroll
            for (int j2 = 0; j2 < 4; ++j2) {
                float x = (j2 == 0) ? v.x : (j2 == 1) ? v.y : (j2 == 2) ? v.z : v.w;
                float s = eo * (1.0f / (1.0f + expf(-x)));
                unsigned int bits = __float_as_uint(s);
                if (bits >= thrBits) {
                    int p = atomicAdd(&s_cnt, 1);
                    if (p < CAP) {
                        cbits[p] = bits;
                        cidx[p] = (q << 8) + (lane << 2) + j2;
                    }
                }
            }
        }
    }
    __syncthreads();
    int M = s_cnt;

    // ---- fallback (exact, any data): binary-search threshold ----
    if (M < TOPK || M > CAP) {
        int lo = 0, hi = NBINS_S - 1;
        while (lo < hi) {
            int mid = (lo + hi + 1) >> 1;
            unsigned int tb = (unsigned int)mid << SHIFT;
            if (tid == 0) s_c2 = 0;
            __syncthreads();
            int local = 0;
            for (int j = wid; j < NQ; j += 16) {
                if (__float_as_uint(eobj[j]) >= tb && lane < 60) {
                    float eo = eobj[j];
                    float4 v = lg4[(j << 6) + lane];
                    local += (__float_as_uint(eo * (1.0f / (1.0f + expf(-v.x)))) >= tb);
                    local += (__float_as_uint(eo * (1.0f / (1.0f + expf(-v.y)))) >= tb);
                    local += (__float_as_uint(eo * (1.0f / (1.0f + expf(-v.z)))) >= tb);
                    local += (__float_as_uint(eo * (1.0f / (1.0f + expf(-v.w)))) >= tb);
                }
            }
            atomicAdd(&s_c2, local);
            __syncthreads();
            if (s_c2 >= TOPK) lo = mid; else hi = mid - 1;
            __syncthreads();
        }
        unsigned int tb = (unsigned int)lo << SHIFT;
        thrBits = tb;
        if (tid == 0) s_cnt = 0;
        __syncthreads();
        for (int j = wid; j < NQ; j += 16) {
            if (__float_as_uint(eobj[j]) >= tb && lane < 60) {
                float eo = eobj[j];
                float4 v = lg4[(j << 6) + lane];
                #pragma unroll
                for (int j2 = 0; j2 < 4; ++j2) {
                    float x = (j2 == 0) ? v.x : (j2 == 1) ? v.y : (j2 == 2) ? v.z : v.w;
                    float s = eo * (1.0f / (1.0f + expf(-x)));
                    unsigned int bits = __float_as_uint(s);
                    if (bits >= tb) {
                        int p = atomicAdd(&s_cnt, 1);
                        if (p < CAP) {
                            cbits[p] = bits;
                            cidx[p] = (j << 8) + (lane << 2) + j2;
                        }
                    }
                }
            }
        }
        __syncthreads();
        M = s_cnt;
    }
    M = min(M, CAP);

    // ---- radix-select: exact TOPK-th largest bits among cbits[0..M) ----
    unsigned int* rhist = part;          // 256
    unsigned int* rsuf  = part + 256;    // 256
    unsigned int prefixVal = 0;
    int need = TOPK;
    int startShift = 24;
    if ((thrBits >> 24) == 0x3Fu) { prefixVal = 0x3F000000u; startShift = 16; }
    for (int shift = startShift; shift >= 0; shift -= 8) {
        if (tid < 256) rhist[tid] = 0;
        __syncthreads();
        unsigned int pmask = (shift >= 24) ? 0u : (0xFFFFFFFFu << (shift + 8));
        for (int i = tid; i < M; i += 1024) {
            unsigned int bb = cbits[i];
            if ((bb & pmask) == (prefixVal & pmask))
                atomicAdd(&rhist[(bb >> shift) & 255], 1u);
        }
        __syncthreads();
        if (tid < 64) {
            unsigned int h0 = rhist[tid * 4 + 0];
            unsigned int h1 = rhist[tid * 4 + 1];
            unsigned int h2 = rhist[tid * 4 + 2];
            unsigned int h3 = rhist[tid * 4 + 3];
            unsigned int loc = h0 + h1 + h2 + h3;
            unsigned int suf = loc;
            #pragma unroll
            for (int d = 1; d < 64; d <<= 1) {
                unsigned int o = __shfl_down(suf, d);
                suf += (tid + d < 64) ? o : 0u;
            }
            unsigned int above = suf - loc;
            rsuf[tid * 4 + 3] = above + h3;
            rsuf[tid * 4 + 2] = above + h3 + h2;
            rsuf[tid * 4 + 1] = above + h3 + h2 + h1;
            rsuf[tid * 4 + 0] = above + h3 + h2 + h1 + h0;
        }
        __syncthreads();
        if (tid < 256) {
            int sv = (int)rsuf[tid];
            int sa = (tid == 255) ? 0 : (int)rsuf[tid + 1];
            if (sv >= need && sa < need) { s_dig = tid; s_above = sa; }
        }
        __syncthreads();
        prefixVal |= ((unsigned int)s_dig) << shift;
        need -= s_above;
    }
    const unsigned int kth = prefixVal;

    // ---- compact survivors (bits >= kth) ----
    unsigned int* fb = pool;
    int* fi = (int*)(pool + FCAP);
    if (tid == 0) s_nfin = 0;
    __syncthreads();
    for (int i = tid; i < M; i += 1024) {
        unsigned int bb = cbits[i];
        if (bb >= kth) {
            int p = atomicAdd(&s_nfin, 1);
            if (p < FCAP) { fb[p] = bb; fi[p] = cidx[i]; }
        }
    }
    __syncthreads();
    const int n = min(s_nfin, FCAP);

    // ---- exact rank over survivors (desc bits, tie -> lower index) ----
    const float ih = tsz[b * 2 + 0];
    const float iw = tsz[b * 2 + 1];
    float* out_scores = out;
    float* out_labels = out + NB * TOPK;
    float* out_boxes  = out + 2 * NB * TOPK;

    for (int i = tid; i < n; i += 1024) {
        unsigned int mb = fb[i];
        int mi = fi[i];
        int rank = 0;
        for (int j = 0; j < n; ++j) {
            unsigned int ob = fb[j];
            int oi = fi[j];
            rank += (ob > mb) || (ob == mb && oi < mi);
        }
        if (rank < TOPK) {
            int q = mi >> 8;
            int c = mi & 255;
            out_scores[b * TOPK + rank] = __uint_as_float(mb);
            out_labels[b * TOPK + rank] = (float)c;
            const float* bp = pboxes + ((size_t)b * NQ + q) * 4;
            float cx = bp[0], cy = bp[1], w = bp[2], h = bp[3];
            float* dst = out_boxes + ((size_t)b * TOPK + rank) * 4;
            dst[0] = (cx - 0.5f * w) * iw;
            dst[1] = (cy - 0.5f * h) * ih;
            dst[2] = (cx + 0.5f * w) * iw;
            dst[3] = (cy + 0.5f * h) * ih;
        }
    }
}

extern "C" void kernel_launch(void* const* d_in, const int* in_sizes, int n_in,
                              void* d_out, int out_size, void* d_ws, size_t ws_size,
                              hipStream_t stream) {
    const float* logits = (const float*)d_in[0];
    const float* obj    = (const float*)d_in[1];
    const float* boxes  = (const float*)d_in[2];
    const float* tsz    = (const float*)d_in[3];
    float* out = (float*)d_out;
    hipLaunchKernelGGL(postproc_kernel, dim3(NB), dim3(1024), 0, stream,
                       logits, obj, boxes, tsz, out);
}